// Round 1
// baseline (884.653 us; speedup 1.0000x reference)
//
#include <hip/hip_runtime.h>

// Problem: 32 chained bottleneck blocks on x[16,256,64,64] fp32.
//   h1 = relu(1x1 conv 256->4 + b1); h2 = relu(3x3 conv 4->4 + b2);
//   xc = relu(1x1 conv 4->256 + b3); acc += xc; repeat with xc as input.
// Strategy: carry only the 4-channel state h1 between steps; fuse
// expand(W3_k)+relu+reduce(W1_{k+1}) per pixel in registers so the
// 256-channel tensor is never materialized except the final acc.
// Store h2_k (1 MiB/block) and compute acc = sum_k relu(W3_k h2_k + b3_k)
// in a final pass.

#define NN 16
#define HH 64
#define WW 64
#define CIN 256
#define CB 4
#define NBLK 32

// ---------------- Phase A: h1_0 = relu(W1_0 . x + b1_0) ------------------
// grid (64,16): blockIdx.x = y, blockIdx.y = n. 256 threads.
// thread: chunk = tid>>6 (c-range of 64), px = tid&63 (x coordinate).
__global__ __launch_bounds__(256) void phaseA(
    const float* __restrict__ x, const float* __restrict__ w1,
    const float* __restrict__ b1, float* __restrict__ h1out) {
  __shared__ float4 w1s[CIN];    // [c] -> o components
  __shared__ float4 part[4][WW]; // [chunk][px] -> o components
  int tid = threadIdx.x;
  for (int i = tid; i < CIN * CB; i += 256) {
    int o = i >> 8, c = i & 255;
    ((float*)&w1s[c])[o] = w1[i]; // w1 global layout [o][c]
  }
  __syncthreads();
  int y = blockIdx.x, n = blockIdx.y;
  int chunk = tid >> 6, px = tid & 63;
  int cbase = chunk * 64;
  const float* xp = x + ((n * CIN + cbase) * HH + y) * WW + px;
  float s0 = 0.f, s1 = 0.f, s2 = 0.f, s3 = 0.f;
#pragma unroll 8
  for (int i = 0; i < 64; ++i) {
    float xv = xp[i * HH * WW];
    float4 wv = w1s[cbase + i];
    s0 = fmaf(xv, wv.x, s0);
    s1 = fmaf(xv, wv.y, s1);
    s2 = fmaf(xv, wv.z, s2);
    s3 = fmaf(xv, wv.w, s3);
  }
  part[chunk][px] = make_float4(s0, s1, s2, s3);
  __syncthreads();
  int px2 = tid >> 2, o = tid & 3;
  float v = ((float*)&part[0][px2])[o] + ((float*)&part[1][px2])[o] +
            ((float*)&part[2][px2])[o] + ((float*)&part[3][px2])[o];
  v += b1[o];
  h1out[((n * HH + y) * WW + px2) * CB + o] = fmaxf(v, 0.f);
}

// ---------------- Phase B: one bottleneck step ---------------------------
// h1in  : [N][H][W][4] state entering block k (already relu(conv1_k ..))
// h2out : [N][H][W][4] slice for block k (consumed by phase C)
// h1out : state for block k+1 (via fused expand+relu+reduce)
// grid (8,8,16): tx,ty tile coords, z = n. 256 threads:
//   px = tid>>2 in 8x8 tile, chunk = tid&3 (c-range 64, interleaved c=cc*4+chunk)
__global__ __launch_bounds__(256) void phaseB(
    const float* __restrict__ h1in, float* __restrict__ h1out,
    float* __restrict__ h2out,
    const float* __restrict__ w2, const float* __restrict__ b2,
    const float* __restrict__ w3, const float* __restrict__ b3,
    const float* __restrict__ w1n, const float* __restrict__ b1n,
    int compute_next) {
  __shared__ float4 h1t[10][10]; // input tile + halo 1, [y][x] -> 4 ch
  __shared__ float4 w2v[36];     // [p=dy*3+dx][i] -> o components
  __shared__ float4 w3v[256];    // [c] -> j components
  __shared__ float4 w1nv[256];   // [c] -> o components
  __shared__ float b3s[256];
  __shared__ float b2s[4], b1ns[4];

  int tid = threadIdx.x;
  int tx = blockIdx.x, ty = blockIdx.y, n = blockIdx.z;
  int y0 = ty * 8, x0 = tx * 8;

  // stage weights
  for (int t = tid; t < 144; t += 256) {
    int o = t / 36, r = t % 36, i = r / 9, p = r % 9;
    ((float*)&w2v[p * 4 + i])[o] = w2[t]; // w2 global [o][i][dy][dx]
  }
  for (int t = tid; t < 1024; t += 256) ((float*)w3v)[t] = w3[t]; // [c][j]
  for (int t = tid; t < 1024; t += 256) {
    int c = t >> 2, o = t & 3;
    ((float*)&w1nv[c])[o] = w1n[o * 256 + c]; // w1n global [o][c]
  }
  if (tid < 256) b3s[tid] = b3[tid];
  if (tid < 4) { b2s[tid] = b2[tid]; b1ns[tid] = b1n[tid]; }
  // stage input tile with zero halo
  for (int t = tid; t < 100; t += 256) {
    int cy = t / 10, cx = t % 10;
    int gy = y0 + cy - 1, gx = x0 + cx - 1;
    float4 v = make_float4(0.f, 0.f, 0.f, 0.f);
    if (gy >= 0 && gy < HH && gx >= 0 && gx < WW)
      v = *(const float4*)&h1in[((n * HH + gy) * WW + gx) * CB];
    h1t[cy][cx] = v;
  }
  __syncthreads();

  int px = tid >> 2, chunk = tid & 3;
  int ly = px >> 3, lx = px & 7;

  // 3x3 conv 4->4 + bias + relu
  float4 hacc = make_float4(b2s[0], b2s[1], b2s[2], b2s[3]);
#pragma unroll
  for (int p = 0; p < 9; ++p) {
    int dy = p / 3, dx = p % 3;
    float4 hv = h1t[ly + dy][lx + dx];
#pragma unroll
    for (int i = 0; i < 4; ++i) {
      float hvi = (i == 0) ? hv.x : (i == 1) ? hv.y : (i == 2) ? hv.z : hv.w;
      float4 wv = w2v[p * 4 + i];
      hacc.x = fmaf(hvi, wv.x, hacc.x);
      hacc.y = fmaf(hvi, wv.y, hacc.y);
      hacc.z = fmaf(hvi, wv.z, hacc.z);
      hacc.w = fmaf(hvi, wv.w, hacc.w);
    }
  }
  float4 h2 = make_float4(fmaxf(hacc.x, 0.f), fmaxf(hacc.y, 0.f),
                          fmaxf(hacc.z, 0.f), fmaxf(hacc.w, 0.f));

  int gy = y0 + ly, gx = x0 + lx;
  int pxg = (n * HH + gy) * WW + gx;
  // store h2 (4 lanes of same px each store one channel -> coalesced)
  float h2sel = (chunk == 0) ? h2.x : (chunk == 1) ? h2.y
              : (chunk == 2) ? h2.z : h2.w;
  h2out[pxg * CB + chunk] = h2sel;

  // fused expand(W3)+relu -> reduce(W1next); each lane covers c = cc*4+chunk
  float4 t = make_float4(0.f, 0.f, 0.f, 0.f);
#pragma unroll 8
  for (int cc = 0; cc < 64; ++cc) {
    int c = (cc << 2) | chunk;
    float4 wv = w3v[c];
    float u = fmaf(h2.w, wv.w,
              fmaf(h2.z, wv.z, fmaf(h2.y, wv.y, fmaf(h2.x, wv.x, b3s[c]))));
    float v = fmaxf(u, 0.f);
    float4 wn = w1nv[c];
    t.x = fmaf(v, wn.x, t.x);
    t.y = fmaf(v, wn.y, t.y);
    t.z = fmaf(v, wn.z, t.z);
    t.w = fmaf(v, wn.w, t.w);
  }
  // reduce partial t over the 4 chunk-lanes of this pixel
  t.x += __shfl_xor(t.x, 1); t.x += __shfl_xor(t.x, 2);
  t.y += __shfl_xor(t.y, 1); t.y += __shfl_xor(t.y, 2);
  t.z += __shfl_xor(t.z, 1); t.z += __shfl_xor(t.z, 2);
  t.w += __shfl_xor(t.w, 1); t.w += __shfl_xor(t.w, 2);
  if (compute_next) {
    float tsel = (chunk == 0) ? t.x : (chunk == 1) ? t.y
               : (chunk == 2) ? t.z : t.w;
    h1out[pxg * CB + chunk] = fmaxf(tsel + b1ns[chunk], 0.f);
  }
}

// ---------------- Phase C: acc = sum_k relu(W3_k h2_k + b3_k) ------------
// grid (4,16,16): x = c-chunk (64 channels), y = ygroup (4 rows), z = n.
// 256 threads: ly = tid>>6, x = tid&63. 64 accumulators per thread.
__global__ __launch_bounds__(256, 4) void phaseC(
    const float* __restrict__ h2buf, const float* __restrict__ w3g,
    const float* __restrict__ b3g, float* __restrict__ out) {
  __shared__ float4 w3c[NBLK * 64]; // [k][cl] -> j components (32 KiB)
  __shared__ float b3c[NBLK * 64]; // 8 KiB
  int tid = threadIdx.x;
  int c0 = blockIdx.x * 64, yg = blockIdx.y, n = blockIdx.z;
  for (int t = tid; t < NBLK * 64; t += 256) {
    int k = t >> 6, cl = t & 63;
    w3c[t] = *(const float4*)&w3g[(k * 256 + c0 + cl) * 4];
    b3c[t] = b3g[k * 256 + c0 + cl];
  }
  __syncthreads();
  int ly = tid >> 6, x = tid & 63;
  int y = yg * 4 + ly;
  float acc[64];
#pragma unroll
  for (int i = 0; i < 64; ++i) acc[i] = 0.f;
  for (int k = 0; k < NBLK; ++k) {
    float4 h = *(const float4*)
        &h2buf[((((k * NN + n) * HH + y) * WW) + x) * CB];
    int kb = k << 6;
#pragma unroll
    for (int cl = 0; cl < 64; ++cl) {
      float4 wv = w3c[kb + cl];
      float u = fmaf(h.w, wv.w,
                fmaf(h.z, wv.z, fmaf(h.y, wv.y, fmaf(h.x, wv.x, b3c[kb + cl]))));
      acc[cl] += fmaxf(u, 0.f);
    }
  }
#pragma unroll 8
  for (int cl = 0; cl < 64; ++cl)
    out[(n * CIN + c0 + cl) * (HH * WW) + y * WW + x] = acc[cl];
}

extern "C" void kernel_launch(void* const* d_in, const int* in_sizes, int n_in,
                              void* d_out, int out_size, void* d_ws, size_t ws_size,
                              hipStream_t stream) {
  const float* x  = (const float*)d_in[0];
  const float* w1 = (const float*)d_in[1]; // [32][4][256]
  const float* b1 = (const float*)d_in[2]; // [32][4]
  const float* w2 = (const float*)d_in[3]; // [32][4][4][3][3]
  const float* b2 = (const float*)d_in[4]; // [32][4]
  const float* w3 = (const float*)d_in[5]; // [32][256][4]
  const float* b3 = (const float*)d_in[6]; // [32][256]
  float* out = (float*)d_out;
  float* ws = (float*)d_ws;

  const int STATE = NN * HH * WW * CB; // 262144 floats = 1 MiB
  float* h1a = ws;
  float* h1b = ws + STATE;
  float* h2  = ws + 2 * STATE; // 32 MiB

  phaseA<<<dim3(HH, NN), 256, 0, stream>>>(x, w1, b1, h1a);
  for (int k = 0; k < NBLK; ++k) {
    const float* hin = (k & 1) ? h1b : h1a;
    float* hout = (k & 1) ? h1a : h1b;
    int kn = (k < NBLK - 1) ? k + 1 : NBLK - 1; // wrapped, unused on last
    phaseB<<<dim3(8, 8, NN), 256, 0, stream>>>(
        hin, hout, h2 + k * STATE,
        w2 + k * 144, b2 + k * CB, w3 + k * 1024, b3 + k * 256,
        w1 + kn * 1024, b1 + kn * CB, (k < NBLK - 1) ? 1 : 0);
  }
  phaseC<<<dim3(4, 16, NN), 256, 0, stream>>>(h2, w3, b3, out);
}